// Round 3
// baseline (121.621 us; speedup 1.0000x reference)
//
#include <hip/hip_runtime.h>

// IrrepsIndexedLinear: y_ir[n,o,i] = alpha * sum_m x_ir[n,m,i] * w[seg(n), ir, m, o]
// N=2048, MUL=128, dims {1,3,5}, G=32, alpha = 1/64.
//
// Round-5: round-2 structure (best measured: 93.6us total, kernel ~8.4us,
// absmax 0.0) + two pure re-indexings. Round-4's W-via-LDS double-buffer
// regressed (barrier-serialized, shallow prefetch, occupancy drop) - reverted.
//
//  (1) o-half split: wave = 16 o-lanes x 4 row-slots (was 32 x 2). Each wave
//      covers 64 o's -> unique W per wave per m = 256B (16 lanes x float4,
//      4-way broadcast), HALVING W L1/L2 traffic (256->128KB/block); the
//      32KB per-half W stream now fits L1 for cross-wave reuse. Instruction
//      and register counts identical to round 2.
//  (2) heavy-light bid remap: static rank order = ir1-core(0..127),
//      ir2-core(128..383), ir0-core(384..447), then likely-dud capacity
//      tails (448..543). bid<256 -> rank=bid; bid in [256,512) ->
//      rank=767-bid; bid>=512 -> rank=bid. bid and bid+256 co-locate on a CU
//      under both mod-256 and XCD-round-robin models -> each CU gets one
//      heavy + one light tile; 3rd blocks (CUs 0-31) are mostly duds.
//      Worst-CU FMA load ~+11% over mean (was ~+43%).
//
//  Per-output summation (m ascending, single FMA chain per output in one
//  thread) is identical to round 2 -> absmax 0.0.

#define NGROUP 32
#define WSTRIDE (128 * 128 * 3) // floats per weight group
#define ALPHA 0.015625f         // 1/sqrt(32*128) = 1/64 exactly

// capacities: cap_ir = NGROUP + NROWS/TR_ir (worst case)
// ir0: TR=32 -> 96 ; ir1: TR=16 -> 160 ; ir2: TR=8 -> 288 ; total 544
#define GRID_BLOCKS 544

#define LDS_FLOATS 6144 // max TR*128*D: ir1 = 16*384 = 6144 (24 KB)

template <int D, int TR, int RP>
__device__ inline void run_ir(int lt, const float* __restrict__ x,
                              const float* __restrict__ w_base_ir, // w + ir off
                              const int* __restrict__ repeats,
                              float* __restrict__ obase, // out + ir out offset
                              float* __restrict__ Xs) {
  // ---- prefetch counts (uniform -> scalar loads, all in flight) ----
  int cnt[NGROUP];
#pragma unroll
  for (int gg = 0; gg < NGROUP; ++gg) cnt[gg] = repeats[gg];

  // ---- group-aligned tile lookup (uniform across block) ----
  int off = 0, g = -1, row0 = 0, nr = 0, tacc = 0;
#pragma unroll
  for (int gg = 0; gg < NGROUP; ++gg) {
    int c = cnt[gg];
    int tg = (c + TR - 1) / TR;
    if (g < 0 && lt < tacc + tg) {
      int tig = lt - tacc;
      g = gg;
      row0 = off + tig * TR;
      nr = min(TR, c - tig * TR);
    }
    tacc += tg;
    off += c;
  }
  if (g < 0) return; // dud block (beyond real tile count) -- uniform exit

  const int tid = threadIdx.x;
  const int lane = tid & 63;
  const int wv = tid >> 6;                   // wave 0..3
  const int h = wv & 1;                      // o-half: o in [h*64, h*64+64)
  const int ol = lane & 15;                  // o-lane: owns o = h*64+ol*4 ..+3
  const int slot = ((wv >> 1) << 2) + (lane >> 4); // row slot 0..7

  constexpr int ROWELEMS = 128 * D;
  constexpr int BMELEMS = TR * ROWELEMS;

  // ---- stage X tile raw into LDS (straight float4 copy; zero-fill > nr) ----
  {
    const float4* xsrc = (const float4*)(x + (size_t)row0 * ROWELEMS);
    float4* xdst = (float4*)Xs;
    const int limit4 = nr * (ROWELEMS / 4);
    constexpr int Q = BMELEMS / 4; // 1024 / 1536 / 1280 -> multiple of 256
    const float4 z = make_float4(0.f, 0.f, 0.f, 0.f);
#pragma unroll
    for (int q = tid; q < Q; q += 256) xdst[q] = (q < limit4) ? xsrc[q] : z;
  }
  __syncthreads();

  // ---- per-thread row constants: r = slot*RP + rr -> (n_loc, i) ----
  int xoff[RP];
  int nloc[RP];
  int iofr[RP];
#pragma unroll
  for (int rr = 0; rr < RP; ++rr) {
    int r = slot * RP + rr;
    int nl = r / D;
    int i = r - nl * D;
    nloc[rr] = nl;
    iofr[rr] = i;
    xoff[rr] = nl * ROWELEMS + i;
  }

  const float* w_g = w_base_ir + (size_t)g * WSTRIDE;
  const float4* wp = (const float4*)w_g + (h * 16 + ol); // per m: +32 float4

  float acc[RP][4];
#pragma unroll
  for (int rr = 0; rr < RP; ++rr)
#pragma unroll
    for (int oj = 0; oj < 4; ++oj) acc[rr][oj] = 0.0f;

  // ---- K loop: no barriers; W streamed from global (L1-hot per o-half),
  //      X broadcast from LDS (16 lanes/address) ----
#pragma unroll 8
  for (int m = 0; m < 128; ++m) {
    const float4 wf = wp[m * 32];
    float xs[RP];
#pragma unroll
    for (int rr = 0; rr < RP; ++rr) xs[rr] = Xs[xoff[rr] + m * D];
#pragma unroll
    for (int rr = 0; rr < RP; ++rr) {
      acc[rr][0] += xs[rr] * wf.x;
      acc[rr][1] += xs[rr] * wf.y;
      acc[rr][2] += xs[rr] * wf.z;
      acc[rr][3] += xs[rr] * wf.w;
    }
  }

  // ---- epilogue: y[n, o, i], o = h*64 + ol*4 + oj ----
  const int ob = h * 64 + ol * 4;
#pragma unroll
  for (int rr = 0; rr < RP; ++rr) {
    if (nloc[rr] < nr) {
      float* orow = obase + (size_t)(row0 + nloc[rr]) * ROWELEMS + iofr[rr];
#pragma unroll
      for (int oj = 0; oj < 4; ++oj)
        orow[(ob + oj) * D] = acc[rr][oj] * ALPHA;
    }
  }
}

__global__ __launch_bounds__(256) void IrrepsIndexedLinear_39161511805249_kernel(
    const float* __restrict__ x0, const float* __restrict__ x1,
    const float* __restrict__ x2, const float* __restrict__ w,
    const int* __restrict__ repeats, float* __restrict__ out) {
  __shared__ float Xs[LDS_FLOATS]; // 24 KB -> 6 blocks/CU capacity

  const int bid = blockIdx.x;
  // heavy-light pairing: bid and bid+256 land on the same CU; give each CU
  // one heavy (rank asc) + one light (rank desc) tile; bids >= 512 take the
  // mostly-dud deep tail.
  const int rank = (bid < 256) ? bid : ((bid < 512) ? (767 - bid) : bid);

  // rank -> (irrep, lt): ir1 core, ir2 core, ir0 core, then capacity tails
  if (rank < 128) {
    run_ir<3, 16, 6>(rank, x1, w + 16384, repeats, out + 262144, Xs);
  } else if (rank < 384) {
    run_ir<5, 8, 5>(rank - 128, x2, w + 32768, repeats, out + 1048576, Xs);
  } else if (rank < 448) {
    run_ir<1, 32, 4>(rank - 384, x0, w, repeats, out, Xs);
  } else if (rank < 480) {
    run_ir<3, 16, 6>(rank - 320, x1, w + 16384, repeats, out + 262144, Xs);
  } else if (rank < 512) {
    run_ir<5, 8, 5>(rank - 224, x2, w + 32768, repeats, out + 1048576, Xs);
  } else {
    run_ir<1, 32, 4>(rank - 448, x0, w, repeats, out, Xs);
  }
}

extern "C" void kernel_launch(void* const* d_in, const int* in_sizes, int n_in,
                              void* d_out, int out_size, void* d_ws, size_t ws_size,
                              hipStream_t stream) {
  const float* x0 = (const float*)d_in[0];
  const float* x1 = (const float*)d_in[1];
  const float* x2 = (const float*)d_in[2];
  const float* w = (const float*)d_in[3];
  const int* repeats = (const int*)d_in[4];
  float* out = (float*)d_out;

  IrrepsIndexedLinear_39161511805249_kernel<<<GRID_BLOCKS, 256, 0, stream>>>(
      x0, x1, x2, w, repeats, out);
}

// Round 4
// 93.837 us; speedup vs baseline: 1.2961x; 1.2961x over previous
//
#include <hip/hip_runtime.h>

// IrrepsIndexedLinear: y_ir[n,o,i] = alpha * sum_m x_ir[n,m,i] * w[seg(n), ir, m, o]
// N=2048 rows, MUL=128 (m and o), dims = {1,3,5}, G=32 groups, alpha = 1/64.
//
// EXACT revert to the measured-best structure (93.6us total; ~85.7us of that
// is two 256MiB harness poison fills at HBM roofline; kernel ~8us, absmax 0.0).
// Rounds 3-5 post-mortems: uniform-TR retile (+4.9us: tripled W bytes/FMA),
// W-via-LDS double-buffer (+10.8us: barrier-serialized, shallow prefetch),
// o-half split + heavy-light remap (+28us: 4-way same-bank X reads, kernel
// latency-serialized at 63us/dispatch). The optimizable kernel slice (~4us
// over the VALU floor) is smaller than the session's fill-drift noise (+-4us);
// this schedule is the empirical optimum.
//
//  - group-aligned row tiles per block (scan repeats[], wave-uniform)
//  - X tile staged RAW into LDS (straight float4 copy: coalesced global reads,
//    conflict-free LDS writes, no integer division)
//  - W is NOT staged: each thread owns output columns to*4..to*4+3 and streams
//    w_g[m*128 + to*4] as float4 directly from global (coalesced across the
//    wave, L1/L2-resident: 64 KB per group reused 8x within the block).
//    => zero barriers in the K-loop.
//  - inner loop per m: 1 global b128 (W) + RP LDS b32 broadcasts (X, 2
//    addresses/wave = conflict-free) + 4*RP FMA
//  - single __syncthreads per block (after X staging).

#define NGROUP 32
#define WSTRIDE (128 * 128 * 3) // floats per weight group
#define ALPHA 0.015625f         // 1/sqrt(32*128) = 1/64 exactly

// tile capacities: cap_ir = NGROUP + NROWS/TR_ir
// ir0: TR=32 -> 96 ; ir1: TR=16 -> 160 ; ir2: TR=8 -> 288 ; total grid 544
#define CAP0 96
#define CAP01 256
#define GRID_BLOCKS 544

#define LDS_FLOATS 6144 // max of TR*128*D: ir1 = 16*384 = 6144 (24 KB)

template <int D, int TR, int RP>
__device__ inline void run_ir(int lt, const float* __restrict__ x,
                              const float* __restrict__ w_base_ir, // w + ir off
                              const int* __restrict__ repeats,
                              float* __restrict__ obase, // out + ir out offset
                              float* __restrict__ Xs) {
  // ---- group-aligned tile lookup (uniform across block) ----
  int off = 0, g = -1, row0 = 0, nr = 0;
  int tacc = 0;
  for (int gg = 0; gg < NGROUP; ++gg) {
    int c = repeats[gg];
    int tg = (c + TR - 1) / TR;
    if (lt < tacc + tg) {
      int tig = lt - tacc;
      g = gg;
      row0 = off + tig * TR;
      nr = min(TR, c - tig * TR);
      break;
    }
    tacc += tg;
    off += c;
  }
  if (g < 0) return; // beyond real tile count for this irrep (whole block)

  const int tid = threadIdx.x;
  const int to = tid & 31; // owns out columns o = to*4 .. to*4+3
  const int tr = tid >> 5; // owns flat rows r = tr*RP .. tr*RP+RP-1

  constexpr int ROWELEMS = 128 * D;
  constexpr int BMELEMS = TR * ROWELEMS;

  // ---- stage X tile raw into LDS (straight copy; zero-fill past nr) ----
  {
    const float4* xsrc = (const float4*)(x + (size_t)row0 * ROWELEMS);
    float4* xdst = (float4*)Xs;
    const int limit4 = nr * (ROWELEMS / 4);
    constexpr int Q = BMELEMS / 4;
    const float4 z = make_float4(0.f, 0.f, 0.f, 0.f);
    for (int q = tid; q < Q; q += 256) xdst[q] = (q < limit4) ? xsrc[q] : z;
  }
  __syncthreads();

  // ---- per-thread row constants: r = tr*RP + rr -> (n_loc, i) ----
  int xoff[RP];
  int nloc[RP];
  int iofr[RP];
#pragma unroll
  for (int rr = 0; rr < RP; ++rr) {
    int r = tr * RP + rr;
    int nl = r / D;
    int i = r - nl * D;
    nloc[rr] = nl;
    iofr[rr] = i;
    xoff[rr] = nl * ROWELEMS + i;
  }

  const float* w_g = w_base_ir + (size_t)g * WSTRIDE;
  const float4* wp = (const float4*)w_g + to; // stride per m: 32 float4s

  float acc[RP][4];
#pragma unroll
  for (int rr = 0; rr < RP; ++rr)
#pragma unroll
    for (int oj = 0; oj < 4; ++oj) acc[rr][oj] = 0.0f;

  // ---- K loop: no barriers; W streamed from global, X broadcast from LDS --
#pragma unroll 8
  for (int m = 0; m < 128; ++m) {
    const float4 wf = wp[m * 32];
    float xs[RP];
#pragma unroll
    for (int rr = 0; rr < RP; ++rr) xs[rr] = Xs[xoff[rr] + m * D];
#pragma unroll
    for (int rr = 0; rr < RP; ++rr) {
      acc[rr][0] += xs[rr] * wf.x;
      acc[rr][1] += xs[rr] * wf.y;
      acc[rr][2] += xs[rr] * wf.z;
      acc[rr][3] += xs[rr] * wf.w;
    }
  }

  // ---- epilogue: y[n, o, i] ----
#pragma unroll
  for (int rr = 0; rr < RP; ++rr) {
    if (nloc[rr] < nr) {
      float* orow = obase + (size_t)(row0 + nloc[rr]) * ROWELEMS + iofr[rr];
#pragma unroll
      for (int oj = 0; oj < 4; ++oj)
        orow[(to * 4 + oj) * D] = acc[rr][oj] * ALPHA;
    }
  }
}

__global__ __launch_bounds__(256) void IrrepsIndexedLinear_39161511805249_kernel(
    const float* __restrict__ x0, const float* __restrict__ x1,
    const float* __restrict__ x2, const float* __restrict__ w,
    const int* __restrict__ repeats, float* __restrict__ out) {
  __shared__ float Xs[LDS_FLOATS]; // 24 KB

  const int bid = blockIdx.x;
  if (bid < CAP0) {
    // ir0: d=1, TR=32, RP=4 ; w offset 0 ; out offset 0
    run_ir<1, 32, 4>(bid, x0, w, repeats, out, Xs);
  } else if (bid < CAP01) {
    // ir1: d=3, TR=16, RP=6 ; w offset 16384 ; out offset 2048*128
    run_ir<3, 16, 6>(bid - CAP0, x1, w + 16384, repeats, out + 262144, Xs);
  } else {
    // ir2: d=5, TR=8, RP=5 ; w offset 32768 ; out offset 2048*128*4
    run_ir<5, 8, 5>(bid - CAP01, x2, w + 32768, repeats, out + 1048576, Xs);
  }
}

extern "C" void kernel_launch(void* const* d_in, const int* in_sizes, int n_in,
                              void* d_out, int out_size, void* d_ws, size_t ws_size,
                              hipStream_t stream) {
  const float* x0 = (const float*)d_in[0];
  const float* x1 = (const float*)d_in[1];
  const float* x2 = (const float*)d_in[2];
  const float* w = (const float*)d_in[3];
  const int* repeats = (const int*)d_in[4];
  float* out = (float*)d_out;

  IrrepsIndexedLinear_39161511805249_kernel<<<GRID_BLOCKS, 256, 0, stream>>>(
      x0, x1, x2, w, repeats, out);
}